// Round 1
// baseline (342.309 us; speedup 1.0000x reference)
//
#include <hip/hip_runtime.h>

// Atom_Atom_embedding_MP: batched KNN (k=16, self-excluded) + 3 message-passing
// layers (concat-features -> 33x33 matvec -> leakyrelu -> sum_k -> 33x16 matvec
// -> GroupNorm(2) -> leakyrelu -> residual).
//
// Structure:
//   prep_kernel : pack xyz into float4 for coalesced candidate loads
//   knn_kernel  : wave-per-query; per-lane register top-16 (sorted desc,
//                 unrolled insert), LDS+shfl 16-round merge
//   layer_kernel: 16 lanes per point (lane = neighbor k); W1 via wave-uniform
//                 s_loads; shfl-tree k-sum; W2 from LDS; shfl GroupNorm
// Workspace: xyz4 | knn_idx | knn_d2 | bufA | bufB  (~4.25 MB)

#define N_PTS 16384
#define D 16
#define DIN 33
#define NEG 0.2f
#define GEPS 1e-5f

__global__ __launch_bounds__(256) void prep_kernel(const float* __restrict__ x,
                                                   float4* __restrict__ xyz4, int n) {
  int i = blockIdx.x * 256 + threadIdx.x;
  if (i < n) xyz4[i] = make_float4(x[3*i], x[3*i+1], x[3*i+2], 0.f);
}

__global__ __launch_bounds__(256) void knn_kernel(const float4* __restrict__ xyz4,
                                                  const int* __restrict__ batch,
                                                  int* __restrict__ knn_idx,
                                                  float* __restrict__ knn_d2, int n) {
  __shared__ float lv[4][16][64];
  __shared__ int   li[4][16][64];
  const int tid = threadIdx.x;
  const int w = tid >> 6;      // wave in block
  const int l = tid & 63;      // lane
  const int q = blockIdx.x * 4 + w;   // query point

  const float4 Q = xyz4[q];
  const int b = batch[q];
  // batch segment [lo, hi) via binary search (batch is sorted)
  int lo, hi;
  { int a = 0, c = n; while (a < c) { int m = (a + c) >> 1; if (batch[m] <  b) a = m + 1; else c = m; } lo = a; }
  { int a = lo, c = n; while (a < c) { int m = (a + c) >> 1; if (batch[m] <= b) a = m + 1; else c = m; } hi = a; }

  // per-lane top-16, sorted DESCENDING (v[0] = current max). all static indices.
  float v[16]; int id[16];
#pragma unroll
  for (int s = 0; s < 16; ++s) { v[s] = 3.0e38f; id[s] = q; }

  for (int j = lo + l; j < hi; j += 64) {
    float4 P = xyz4[j];
    float dx = Q.x - P.x, dy = Q.y - P.y, dz = Q.z - P.z;
    float d2 = dx*dx + dy*dy + dz*dz;
    if (j != q && d2 < v[0]) {
      // drop current max, insert d2 keeping sorted-descending order
#pragma unroll
      for (int s = 0; s < 16; ++s) {
        float vs = v[s];
        float vn = (s < 15) ? v[s+1] : -3.0e38f;
        int  idn = (s < 15) ? id[s+1] : 0;
        bool stay = (vs <= d2);
        bool up   = (vn > d2);
        v[s]  = stay ? vs    : (up ? vn  : d2);
        id[s] = stay ? id[s] : (up ? idn : j);
      }
    }
  }

  // dump per-lane lists to LDS in ASCENDING order
#pragma unroll
  for (int s = 0; s < 16; ++s) { lv[w][15 - s][l] = v[s]; li[w][15 - s][l] = id[s]; }
  __syncthreads();

  // 16-round extract-min merge across the 64 lanes
  int head = 0;
  float rv = 0.f; int ri = q;
  for (int r = 0; r < 16; ++r) {
    float bv = lv[w][head][l];
    int   bi = li[w][head][l];
    int   bl = l;
#pragma unroll
    for (int m = 1; m < 64; m <<= 1) {
      float ov = __shfl_xor(bv, m);
      int   oi = __shfl_xor(bi, m);
      int   ol = __shfl_xor(bl, m);
      if (ov < bv || (ov == bv && ol < bl)) { bv = ov; bi = oi; bl = ol; }
    }
    if (l == bl) head++;          // winner advances its head
    if (l == r)  { rv = bv; ri = bi; }
  }
  if (l < 16) {
    knn_idx[q * 16 + l] = ri;
    knn_d2 [q * 16 + l] = rv;
  }
}

__device__ __forceinline__ void load16(const float4* __restrict__ base, int row, float* dst) {
  float4 a = base[row*4+0], b = base[row*4+1], c = base[row*4+2], d = base[row*4+3];
  dst[0]=a.x;  dst[1]=a.y;  dst[2]=a.z;  dst[3]=a.w;
  dst[4]=b.x;  dst[5]=b.y;  dst[6]=b.z;  dst[7]=b.w;
  dst[8]=c.x;  dst[9]=c.y;  dst[10]=c.z; dst[11]=c.w;
  dst[12]=d.x; dst[13]=d.y; dst[14]=d.z; dst[15]=d.w;
}

__device__ __forceinline__ float lrelu(float x) {
  return fmaxf(x, 0.f) + NEG * fminf(x, 0.f);
}

__global__ __launch_bounds__(256) void layer_kernel(
    const float* __restrict__ in, const int* __restrict__ knn_idx,
    const float* __restrict__ knn_d2,
    const float* __restrict__ W1, const float* __restrict__ b1,
    const float* __restrict__ W2, const float* __restrict__ b2,
    const float* __restrict__ gamma, const float* __restrict__ beta,
    float* __restrict__ outb) {
  __shared__ float sW2[DIN * D];
  __shared__ float sb2[D], sg[D], sbt[D];
  const int tid = threadIdx.x;
  for (int t = tid; t < DIN * D; t += 256) sW2[t] = W2[t];
  if (tid < D) { sb2[tid] = b2[tid]; sg[tid] = gamma[tid]; sbt[tid] = beta[tid]; }
  __syncthreads();

  const int p = blockIdx.x * 16 + (tid >> 4);  // point
  const int c = tid & 15;                       // lane-col == neighbor index k
  const float4* in4 = (const float4*)in;

  float s[16], nf[16];
  load16(in4, p, s);                 // own features (broadcast within 16-group)
  const int   nb = knn_idx[p * 16 + c];
  const float dk = knn_d2 [p * 16 + c];
  load16(in4, nb, nf);               // neighbor features (gather)

  // h = leakyrelu(feat @ W1 + b1); feat = [s | nf | dk].  W1 reads are
  // wave-uniform -> scalar loads; accumulators fully unrolled in VGPRs.
  float h[DIN];
#pragma unroll
  for (int o = 0; o < DIN; ++o) h[o] = b1[o] + dk * W1[32 * DIN + o];
#pragma unroll
  for (int i = 0; i < 16; ++i) {
    const float si = s[i], ni = nf[i];
#pragma unroll
    for (int o = 0; o < DIN; ++o) {
      h[o] += si * W1[i * DIN + o];
      h[o] += ni * W1[(16 + i) * DIN + o];
    }
  }
#pragma unroll
  for (int o = 0; o < DIN; ++o) h[o] = lrelu(h[o]);

  // sum h over the 16 neighbors (lanes of the 16-group)
#pragma unroll
  for (int o = 0; o < DIN; ++o) {
    float x = h[o];
    x += __shfl_xor(x, 1);
    x += __shfl_xor(x, 2);
    x += __shfl_xor(x, 4);
    x += __shfl_xor(x, 8);
    h[o] = x;
  }

  // msg[c] = hs @ W2[:,c] + b2[c]   (per-lane output column)
  float m = sb2[c];
#pragma unroll
  for (int i = 0; i < DIN; ++i) m += h[i] * sW2[i * D + c];

  // GroupNorm(groups=2): channels 0-7 and 8-15 -> 8-lane shfl reductions
  float sum = m;
  sum += __shfl_xor(sum, 1); sum += __shfl_xor(sum, 2); sum += __shfl_xor(sum, 4);
  const float mu = sum * 0.125f;
  const float dd = m - mu;
  float sq = dd * dd;
  sq += __shfl_xor(sq, 1); sq += __shfl_xor(sq, 2); sq += __shfl_xor(sq, 4);
  const float var = sq * 0.125f;
  float yv = dd * (1.0f / sqrtf(var + GEPS));
  yv = yv * sg[c] + sbt[c];

  const float selfc = in[p * 16 + c];
  outb[p * 16 + c] = selfc + lrelu(yv);
}

extern "C" void kernel_launch(void* const* d_in, const int* in_sizes, int n_in,
                              void* d_out, int out_size, void* d_ws, size_t ws_size,
                              hipStream_t stream) {
  const float* x     = (const float*)d_in[0];
  const float* yat   = (const float*)d_in[2];
  const float* W1    = (const float*)d_in[3];
  const float* b1    = (const float*)d_in[4];
  const float* W2    = (const float*)d_in[5];
  const float* b2    = (const float*)d_in[6];
  const float* gamma = (const float*)d_in[7];
  const float* beta  = (const float*)d_in[8];
  const int*   xb    = (const int*)d_in[9];
  float* out = (float*)d_out;

  char* ws = (char*)d_ws;
  float4* xyz4 = (float4*)(ws);
  int*    kidx = (int*)  (ws + 262144);
  float*  kd2  = (float*)(ws + 262144 + 1048576);
  float*  bufA = (float*)(ws + 262144 + 2*1048576);
  float*  bufB = (float*)(ws + 262144 + 3*1048576);

  prep_kernel<<<N_PTS / 256, 256, 0, stream>>>(x, xyz4, N_PTS);
  knn_kernel<<<N_PTS / 4, 256, 0, stream>>>(xyz4, xb, kidx, kd2, N_PTS);
  layer_kernel<<<N_PTS / 16, 256, 0, stream>>>(yat,  kidx, kd2,
      W1 + 0*DIN*DIN, b1 + 0*DIN, W2 + 0*DIN*D, b2 + 0*D, gamma + 0*D, beta + 0*D, bufA);
  layer_kernel<<<N_PTS / 16, 256, 0, stream>>>(bufA, kidx, kd2,
      W1 + 1*DIN*DIN, b1 + 1*DIN, W2 + 1*DIN*D, b2 + 1*D, gamma + 1*D, beta + 1*D, bufB);
  layer_kernel<<<N_PTS / 16, 256, 0, stream>>>(bufB, kidx, kd2,
      W1 + 2*DIN*DIN, b1 + 2*DIN, W2 + 2*DIN*D, b2 + 2*D, gamma + 2*D, beta + 2*D, out);
}